// Round 15
// baseline (138.817 us; speedup 1.0000x reference)
//
#include <hip/hip_runtime.h>

#define B_ 8
#define S_ 4096
#define D_ 128
#define KVB 64
#define NT (S_ / KVB)

typedef __attribute__((ext_vector_type(4))) float f32x4;
typedef __attribute__((ext_vector_type(16))) float f32x16;
typedef __attribute__((ext_vector_type(8))) short s16x8;

__device__ __forceinline__ unsigned short f2bf(float f) {
    union { float f; unsigned u; } v; v.f = f;
    unsigned r = (v.u + 0x7fffu + ((v.u >> 16) & 1u)) >> 16;
    return (unsigned short)r;
}

// packed f32x2 -> bf16x2 (RNE), single VALU op
__device__ __forceinline__ unsigned cvt_pk(float lo, float hi) {
    unsigned r;
    asm("v_cvt_pk_bf16_f32 %0, %1, %2" : "=v"(r) : "v"(lo), "v"(hi));
    return r;
}

__device__ __forceinline__ s16x8 load_cvt8(const float* p) {
    f32x4 a = *(const f32x4*)p;
    f32x4 b = *(const f32x4*)(p + 4);
    s16x8 r;
    r[0] = (short)f2bf(a[0]); r[1] = (short)f2bf(a[1]);
    r[2] = (short)f2bf(a[2]); r[3] = (short)f2bf(a[3]);
    r[4] = (short)f2bf(b[0]); r[5] = (short)f2bf(b[1]);
    r[6] = (short)f2bf(b[2]); r[7] = (short)f2bf(b[3]);
    return r;
}

// async global->LDS, 16B per lane. lds must be wave-uniform base; HW adds lane*16.
__device__ __forceinline__ void gld16(unsigned short* lds, const unsigned short* g) {
    __builtin_amdgcn_global_load_lds(
        (const __attribute__((address_space(1))) unsigned int*)g,
        (__attribute__((address_space(3))) unsigned int*)lds,
        16, 0, 0);
}

// ---------------------------------------------------------------------------
// Kernel 1: q/k/v projections + layernorm(q,k), bf16 outputs, v transposed.
// q is pre-scaled by (1/sqrt(D)) * log2(e) so attention works in exp2 domain.
// ---------------------------------------------------------------------------
__global__ __launch_bounds__(256, 1) void proj_kernel(
    const float* __restrict__ x,  const float* __restrict__ Wq,
    const float* __restrict__ Wk, const float* __restrict__ Wv,
    const float* __restrict__ qn_w, const float* __restrict__ qn_b,
    const float* __restrict__ kn_w, const float* __restrict__ kn_b,
    unsigned short* __restrict__ qo, unsigned short* __restrict__ ko,
    unsigned short* __restrict__ vto)
{
    __shared__ unsigned short wlds[128 * 136];
    __shared__ unsigned short vstage[128 * 72];

    const int tid  = threadIdx.x;
    const int lane = tid & 63;
    const int wv   = tid >> 6;
    const int j    = lane & 15;
    const int g    = lane >> 4;

    const int b    = blockIdx.x >> 6;
    const int sblk = (blockIdx.x & 63) * 64;
    const int srow = sblk + wv * 16;

    const float* xrow = x + ((size_t)b * S_ + srow + j) * D_;
    s16x8 af[4];
#pragma unroll
    for (int kk = 0; kk < 4; ++kk) af[kk] = load_cvt8(xrow + kk * 32 + g * 8);

    const int wrow = tid >> 1;
    const int wcol = (tid & 1) * 64;

#pragma unroll 1
    for (int m = 0; m < 3; ++m) {
        const float* Wm = (m == 0) ? Wq : (m == 1) ? Wk : Wv;
        __syncthreads();
#pragma unroll
        for (int it = 0; it < 8; ++it) {
            int col = wcol + it * 8;
            *(s16x8*)&wlds[wrow * 136 + col] = load_cvt8(Wm + wrow * 128 + col);
        }
        __syncthreads();

        f32x4 acc[8];
#pragma unroll
        for (int ct = 0; ct < 8; ++ct) { f32x4 z = {0.f, 0.f, 0.f, 0.f}; acc[ct] = z; }
#pragma unroll
        for (int ct = 0; ct < 8; ++ct) {
#pragma unroll
            for (int kk = 0; kk < 4; ++kk) {
                s16x8 bf = *(const s16x8*)&wlds[(ct * 16 + j) * 136 + kk * 32 + g * 8];
                acc[ct] = __builtin_amdgcn_mfma_f32_16x16x32_bf16(af[kk], bf, acc[ct], 0, 0, 0);
            }
        }

        if (m < 2) {
            const float* lw = (m == 0) ? qn_w : kn_w;
            const float* lb = (m == 0) ? qn_b : kn_b;
            float sum[4], sq[4];
#pragma unroll
            for (int r = 0; r < 4; ++r) {
                float s1 = 0.f, s2 = 0.f;
#pragma unroll
                for (int ct = 0; ct < 8; ++ct) { float v = acc[ct][r]; s1 += v; s2 += v * v; }
#pragma unroll
                for (int msk = 1; msk < 16; msk <<= 1) {
                    s1 += __shfl_xor(s1, msk);
                    s2 += __shfl_xor(s2, msk);
                }
                sum[r] = s1; sq[r] = s2;
            }
            float gwv[8], gbv[8];
#pragma unroll
            for (int ct = 0; ct < 8; ++ct) { gwv[ct] = lw[ct * 16 + j]; gbv[ct] = lb[ct * 16 + j]; }
            unsigned short* dst = (m == 0) ? qo : ko;
            // q: fold 1/sqrt(128) * log2(e) so scores are in exp2 domain
            const float post = (m == 0) ? 0.12751742361888f : 1.0f;
#pragma unroll
            for (int r = 0; r < 4; ++r) {
                float mean = sum[r] * (1.f / 128.f);
                float var  = sq[r] * (1.f / 128.f) - mean * mean;
                float rstd = rsqrtf(var + 1e-5f);
                size_t rowoff = ((size_t)b * S_ + sblk + wv * 16 + g * 4 + r) * D_;
#pragma unroll
                for (int ct = 0; ct < 8; ++ct) {
                    float val = ((acc[ct][r] - mean) * rstd * gwv[ct] + gbv[ct]) * post;
                    dst[rowoff + ct * 16 + j] = f2bf(val);
                }
            }
        } else {
#pragma unroll
            for (int ct = 0; ct < 8; ++ct) {
#pragma unroll
                for (int r = 0; r < 4; ++r) {
                    vstage[(ct * 16 + j) * 72 + wv * 16 + g * 4 + r] = f2bf(acc[ct][r]);
                }
            }
            __syncthreads();
            int h  = tid >> 1;
            int cb = (tid & 1) * 32;
#pragma unroll
            for (int c = 0; c < 4; ++c) {
                *(s16x8*)(vto + ((size_t)b * D_ + h) * S_ + sblk + cb + c * 8) =
                    *(const s16x8*)&vstage[h * 72 + cb + c * 8];
            }
        }
    }
}

// ---------------------------------------------------------------------------
// Kernel 2: flash attention, 64 q-rows/wave on 32x32x16 MFMAs (r9's verified
// zero-shuffle machinery), split-K x2, T15 pipeline, 3-buffer single-barrier
// staging. r14 structure with the epilogue LDS layout FIXED:
// - combine needs csum 64KB + lsum 16KB = 80KB; r14 pointed csum at a 48KB
//   region -> overlap with lsum + overflow (the correctness failure).
//   Now one flat 96KB smem array: main loop aliases kbuf (3x16KB) and vbuf
//   (3x2x8KB) views; epilogue uses csum = floats [0,16384), lsum = floats
//   [16384, 20480) -- disjoint, in-bounds.
// - Wave (qg,kh) = 64 q-rows (2 fragment sets of 32) x 32-k half: each K/V
//   fragment feeds 2 q-sets in registers -> LDS read bytes per CU-tile halve
//   vs q=32/wave.
// - 3 LDS buffers: STAGE(t+2) targets the buffer last read at t-1 (drained
//   before barrier(t) by latency margin: write issues >=600cy later + global
//   fetch latency) -> ONE barrier per tile, no lgkm drain, counted vmcnt(8).
// - QK^T = mfma32(K_perm, Q), pa permutation (swap 4-blocks 1<->2 per 16):
//   P lands in PV A-fragment order, zero cross-lane ops. Linear no-max
//   softmax (LayerNorm bounds |s*log2e| <= 16.4), ones-MFMA row-sum, exp2
//   domain, v_cvt_pk_bf16_f32.
// - LDS: K [64][128] slot ^= row&15; V sub-tiled [3][ksub][128][32] 64B rows,
//   slot ^= (row^(row>>2))&3 (both r11-measured conflict-free).
// Block: 4 waves = 2 qg x 2 kh, 128 q-rows. Grid 256 = 1 block/CU.
// ---------------------------------------------------------------------------
__global__ __launch_bounds__(256, 1) void attn_kernel(
    const unsigned short* __restrict__ qb, const unsigned short* __restrict__ kb,
    const unsigned short* __restrict__ vtb, float* __restrict__ out)
{
    // flat 96 KiB: [0, 24576) shorts = K buffers, [24576, 49152) = V buffers
    __shared__ unsigned short smem[49152];
    unsigned short* kb_ = smem;                       // kbuf[bi] = kb_ + bi*8192
    unsigned short* vb_ = smem + 3 * KVB * D_;        // vbuf[bi][ksub] = vb_ + (bi*2+ksub)*4096

    const int tid  = threadIdx.x;
    const int lane = tid & 63;
    const int wv   = tid >> 6;          // 0..3
    const int qg   = wv & 1;            // q-group (64 rows)
    const int kh   = wv >> 1;           // k-half (32 of 64)
    const int a    = lane & 31;
    const int hh   = lane >> 5;         // 0..1

    // K-row permutation pi: swap 4-blocks 1<->2 within each 16 (r9-verified)
    const int blk = (a >> 2) & 3;
    const int pa  = (blk == 1) ? a + 4 : (blk == 2) ? a - 4 : a;

    // bijective XCD swizzle (256 % 8 == 0)
    const int swz = (blockIdx.x & 7) * 32 + (blockIdx.x >> 3);
    const int b   = swz >> 5;
    const int s0  = (swz & 31) * 128;   // 128 q-rows per block

    // Q fragments: set 0 -> q = s0 + qg*64 + a, set 1 -> +32
    const unsigned short* qp0 = qb + ((size_t)b * S_ + s0 + qg * 64 + a) * D_;
    const unsigned short* qp1 = qp0 + 32 * D_;
    s16x8 qf0[8], qf1[8];
#pragma unroll
    for (int kk = 0; kk < 8; ++kk) {
        qf0[kk] = *(const s16x8*)(qp0 + kk * 16 + hh * 8);
        qf1[kk] = *(const s16x8*)(qp1 + kk * 16 + hh * 8);
    }

    const unsigned short* kg_base = kb  + (size_t)b * S_ * D_;
    const unsigned short* vg_base = vtb + (size_t)b * D_ * S_;

    // stage tile kt2 into buffer bi: 8 gld16/wave (4 K + 4 V)
    auto STAGE = [&](int bi, int kt2) {
        const int kv0 = kt2 * KVB;
        unsigned short* kdst = kb_ + bi * (KVB * D_);
#pragma unroll
        for (int it = 0; it < 4; ++it) {                 // K: 4 rows per issue
            const int row = wv * 16 + it * 4 + (lane >> 4);
            const unsigned short* src =
                kg_base + (size_t)(kv0 + row) * D_ + (((lane & 15) ^ (row & 15)) << 3);
            gld16(kdst + (wv * 16 + it * 4) * D_, src);
        }
        // V: wave handles ksub = wv&1, d-rows 64*(wv>>1) + it*16 .. +16
        const int ksub = wv & 1;
        const int rb   = 64 * (wv >> 1);
        unsigned short* vdst = vb_ + (bi * 2 + ksub) * (D_ * 32);
#pragma unroll
        for (int it = 0; it < 4; ++it) {
            const int row = rb + it * 16 + (lane >> 2);
            const int gg  = (row ^ (row >> 2)) & 3;
            const unsigned short* src =
                vg_base + (size_t)row * S_ + kv0 + ksub * 32 + (((lane & 3) ^ gg) << 3);
            gld16(vdst + (rb + it * 16) * 32, src);
        }
    };

    STAGE(0, 0);
    STAGE(1, 1);

    f32x16 acc[2][4], ld[2];
#pragma unroll
    for (int qs = 0; qs < 2; ++qs) {
#pragma unroll
        for (int dt = 0; dt < 4; ++dt)
#pragma unroll
            for (int e = 0; e < 16; ++e) acc[qs][dt][e] = 0.f;
#pragma unroll
        for (int e = 0; e < 16; ++e) ld[qs][e] = 0.f;
    }

    // ones B-fragment (bf16 1.0 = 0x3F80) for the row-sum MFMA
    s16x8 ones;
#pragma unroll
    for (int e = 0; e < 8; ++e) ones[e] = (short)0x3F80;

    // loop-invariant addressing (r9/r11-verified)
    const int kbase = (32 * kh + pa) * D_;   // permuted K row for this lane
    const int kswz  = pa & 15;
    const int vswz  = (a ^ (a >> 2)) & 3;    // fV(row) for row = 32dt + a

    // pipeline state carried across iterations
    s16x8 vfr[8];                        // V frags of tile t: [dt][km]
    union PU { unsigned u[4]; s16x8 v; };
    PU P0a, P1a, P0b, P1b;               // P frags of tile t, q-sets a/b

    // PV + row-sum for the PREVIOUS tile: pure register MFMAs (20)
    auto PV_PREV = [&]() {
        __builtin_amdgcn_s_setprio(1);
        ld[0] = __builtin_amdgcn_mfma_f32_32x32x16_bf16(P0a.v, ones, ld[0], 0, 0, 0);
        ld[0] = __builtin_amdgcn_mfma_f32_32x32x16_bf16(P1a.v, ones, ld[0], 0, 0, 0);
        ld[1] = __builtin_amdgcn_mfma_f32_32x32x16_bf16(P0b.v, ones, ld[1], 0, 0, 0);
        ld[1] = __builtin_amdgcn_mfma_f32_32x32x16_bf16(P1b.v, ones, ld[1], 0, 0, 0);
#pragma unroll
        for (int dt = 0; dt < 4; ++dt) {
            acc[0][dt] = __builtin_amdgcn_mfma_f32_32x32x16_bf16(P0a.v, vfr[dt * 2 + 0], acc[0][dt], 0, 0, 0);
            acc[0][dt] = __builtin_amdgcn_mfma_f32_32x32x16_bf16(P1a.v, vfr[dt * 2 + 1], acc[0][dt], 0, 0, 0);
            acc[1][dt] = __builtin_amdgcn_mfma_f32_32x32x16_bf16(P0b.v, vfr[dt * 2 + 0], acc[1][dt], 0, 0, 0);
            acc[1][dt] = __builtin_amdgcn_mfma_f32_32x32x16_bf16(P1b.v, vfr[dt * 2 + 1], acc[1][dt], 0, 0, 0);
        }
        __builtin_amdgcn_s_setprio(0);
    };

    int cur = 0;                          // kt % 3
#pragma unroll 1
    for (int kt = 0; kt < NT; ++kt) {
        // tile t's 8 loads retired (t+1's 8 may remain in flight)
        if (kt + 1 < NT) { asm volatile("s_waitcnt vmcnt(8)" ::: "memory"); }
        else             { asm volatile("s_waitcnt vmcnt(0)" ::: "memory"); }
        __builtin_amdgcn_s_barrier();
        asm volatile("" ::: "memory");

        const unsigned short* kl = kb_ + cur * (KVB * D_);
        const unsigned short* vl = vb_ + (cur * 2 + kh) * (D_ * 32);

        // K fragment reads (8; latency hidden by PV below)
        s16x8 kf[8];
#pragma unroll
        for (int kk = 0; kk < 8; ++kk)
            kf[kk] = *(const s16x8*)&kl[kbase + (((2 * kk + hh) ^ kswz) << 3)];

        // PV of previous tile (register-only; overlaps K-read latency)
        if (kt) PV_PREV();

        // V fragment loads for THIS tile (consumed at t+1)
#pragma unroll
        for (int dt = 0; dt < 4; ++dt)
#pragma unroll
            for (int km = 0; km < 2; ++km)
                vfr[dt * 2 + km] = *(const s16x8*)
                    &vl[(32 * dt + a) * 32 + (((2 * km + hh) ^ vswz) << 3)];

        // QK^T: four independent 4-deep chains (2 q-sets x low/high d)
        f32x16 svA0, svB0, svA1, svB1;
#pragma unroll
        for (int e = 0; e < 16; ++e) { svA0[e] = 0.f; svB0[e] = 0.f; svA1[e] = 0.f; svB1[e] = 0.f; }
        __builtin_amdgcn_s_setprio(1);
#pragma unroll
        for (int kk = 0; kk < 4; ++kk) {
            svA0 = __builtin_amdgcn_mfma_f32_32x32x16_bf16(kf[kk],     qf0[kk],     svA0, 0, 0, 0);
            svA1 = __builtin_amdgcn_mfma_f32_32x32x16_bf16(kf[kk],     qf1[kk],     svA1, 0, 0, 0);
            svB0 = __builtin_amdgcn_mfma_f32_32x32x16_bf16(kf[kk + 4], qf0[kk + 4], svB0, 0, 0, 0);
            svB1 = __builtin_amdgcn_mfma_f32_32x32x16_bf16(kf[kk + 4], qf1[kk + 4], svB1, 0, 0, 0);
        }
        __builtin_amdgcn_s_setprio(0);

        // prefetch tile t+2 into the buffer last read at t-1 -- DMA issue
        // overlaps exp2/cvt below
        if (kt + 2 < NT) {
            int nxt = cur + 2; if (nxt >= 3) nxt -= 3;
            STAGE(nxt, kt + 2);
        }

        // no max tracking: P = exp2(s) directly (LayerNorm bounds |s| <= 16.4)
        float p0[16], p1[16];
#pragma unroll
        for (int e = 0; e < 16; ++e) {
            p0[e] = exp2f(svA0[e] + svB0[e]);
            p1[e] = exp2f(svA1[e] + svB1[e]);
        }
        P0a.u[0] = cvt_pk(p0[0],  p0[1]);  P0a.u[1] = cvt_pk(p0[2],  p0[3]);
        P0a.u[2] = cvt_pk(p0[4],  p0[5]);  P0a.u[3] = cvt_pk(p0[6],  p0[7]);
        P1a.u[0] = cvt_pk(p0[8],  p0[9]);  P1a.u[1] = cvt_pk(p0[10], p0[11]);
        P1a.u[2] = cvt_pk(p0[12], p0[13]); P1a.u[3] = cvt_pk(p0[14], p0[15]);
        P0b.u[0] = cvt_pk(p1[0],  p1[1]);  P0b.u[1] = cvt_pk(p1[2],  p1[3]);
        P0b.u[2] = cvt_pk(p1[4],  p1[5]);  P0b.u[3] = cvt_pk(p1[6],  p1[7]);
        P1b.u[0] = cvt_pk(p1[8],  p1[9]);  P1b.u[1] = cvt_pk(p1[10], p1[11]);
        P1b.u[2] = cvt_pk(p1[12], p1[13]); P1b.u[3] = cvt_pk(p1[14], p1[15]);

        ++cur; if (cur == 3) cur = 0;
    }

    // drain the pipeline: PV of the last tile
    PV_PREV();

    // all waves done with the k/v buffers before reusing them for the combine
    __syncthreads();

    // ---- split-k combine (fixed layout): csum = floats [0, 16384) (64KB),
    //      lsum = floats [16384, 20480) (16KB); both inside the 96KB smem.
    float* csum = (float*)smem;
    float* lsum = (float*)smem + 16384;
    if (kh == 1) {
#pragma unroll
        for (int qs = 0; qs < 2; ++qs) {
#pragma unroll
            for (int dt = 0; dt < 4; ++dt)
                *(f32x16*)&csum[(((qg * 2 + qs) * 4 + dt) * 64 + lane) * 16] = acc[qs][dt];
            *(f32x16*)&lsum[((qg * 2 + qs) * 64 + lane) * 16] = ld[qs];
        }
    }
    __syncthreads();
    if (kh == 0) {
#pragma unroll
        for (int qs = 0; qs < 2; ++qs) {
            f32x16 lt = *(const f32x16*)&lsum[((qg * 2 + qs) * 64 + lane) * 16];
            float li[16];
#pragma unroll
            for (int r = 0; r < 16; ++r) li[r] = 1.0f / (ld[qs][r] + lt[r]);
#pragma unroll
            for (int dt = 0; dt < 4; ++dt) {
                f32x16 o = *(const f32x16*)&csum[(((qg * 2 + qs) * 4 + dt) * 64 + lane) * 16];
#pragma unroll
                for (int r = 0; r < 16; ++r) {
                    const int qrow = (r & 3) + 8 * (r >> 2) + 4 * hh;
                    out[((size_t)b * S_ + s0 + qg * 64 + qs * 32 + qrow) * D_ + 32 * dt + a] =
                        (acc[qs][dt][r] + o[r]) * li[r];
                }
            }
        }
    }
}

extern "C" void kernel_launch(void* const* d_in, const int* in_sizes, int n_in,
                              void* d_out, int out_size, void* d_ws, size_t ws_size,
                              hipStream_t stream) {
    const float* x    = (const float*)d_in[0];
    const float* Wq   = (const float*)d_in[1];
    const float* Wk   = (const float*)d_in[2];
    const float* Wv   = (const float*)d_in[3];
    const float* qn_w = (const float*)d_in[4];
    const float* qn_b = (const float*)d_in[5];
    const float* kn_w = (const float*)d_in[6];
    const float* kn_b = (const float*)d_in[7];
    float* out = (float*)d_out;

    const size_t n = (size_t)B_ * S_ * D_;
    unsigned short* qws  = (unsigned short*)d_ws;
    unsigned short* kws  = qws + n;
    unsigned short* vtws = kws + n;

    proj_kernel<<<512, 256, 0, stream>>>(x, Wq, Wk, Wv, qn_w, qn_b, kn_w, kn_b,
                                         qws, kws, vtws);
    attn_kernel<<<256, 256, 0, stream>>>(qws, kws, vtws, out);
}

// Round 16
// 116.978 us; speedup vs baseline: 1.1867x; 1.1867x over previous
//
#include <hip/hip_runtime.h>

#define B_ 8
#define S_ 4096
#define D_ 128
#define KVB 64
#define NT (S_ / KVB)

typedef __attribute__((ext_vector_type(4))) float f32x4;
typedef __attribute__((ext_vector_type(8))) short s16x8;

__device__ __forceinline__ unsigned short f2bf(float f) {
    union { float f; unsigned u; } v; v.f = f;
    unsigned r = (v.u + 0x7fffu + ((v.u >> 16) & 1u)) >> 16;
    return (unsigned short)r;
}

// packed f32x2 -> bf16x2 (RNE), single VALU op
__device__ __forceinline__ unsigned cvt_pk(float lo, float hi) {
    unsigned r;
    asm("v_cvt_pk_bf16_f32 %0, %1, %2" : "=v"(r) : "v"(lo), "v"(hi));
    return r;
}

__device__ __forceinline__ s16x8 load_cvt8(const float* p) {
    f32x4 a = *(const f32x4*)p;
    f32x4 b = *(const f32x4*)(p + 4);
    s16x8 r;
    r[0] = (short)f2bf(a[0]); r[1] = (short)f2bf(a[1]);
    r[2] = (short)f2bf(a[2]); r[3] = (short)f2bf(a[3]);
    r[4] = (short)f2bf(b[0]); r[5] = (short)f2bf(b[1]);
    r[6] = (short)f2bf(b[2]); r[7] = (short)f2bf(b[3]);
    return r;
}

// async global->LDS, 16B per lane. lds must be wave-uniform base; HW adds lane*16.
__device__ __forceinline__ void gld16(unsigned short* lds, const unsigned short* g) {
    __builtin_amdgcn_global_load_lds(
        (const __attribute__((address_space(1))) unsigned int*)g,
        (__attribute__((address_space(3))) unsigned int*)lds,
        16, 0, 0);
}

// ---------------------------------------------------------------------------
// Kernel 1: q/k/v projections + layernorm(q,k), bf16 outputs, v transposed.
// q is pre-scaled by (1/sqrt(D)) * log2(e) so attention works in exp2 domain.
// x is staged through LDS with coalesced f32x4 loads (the direct A-fragment
// pattern was 32B/lane at 512B stride = heavy over-fetch on 16MB of fp32).
// ---------------------------------------------------------------------------
__global__ __launch_bounds__(256, 1) void proj_kernel(
    const float* __restrict__ x,  const float* __restrict__ Wq,
    const float* __restrict__ Wk, const float* __restrict__ Wv,
    const float* __restrict__ qn_w, const float* __restrict__ qn_b,
    const float* __restrict__ kn_w, const float* __restrict__ kn_b,
    unsigned short* __restrict__ qo, unsigned short* __restrict__ ko,
    unsigned short* __restrict__ vto)
{
    __shared__ unsigned short wlds[128 * 136];
    __shared__ unsigned short vstage[128 * 72];
    __shared__ float xlds[64 * 132];          // 64 rows x 128 cols, pad->132

    const int tid  = threadIdx.x;
    const int lane = tid & 63;
    const int wv   = tid >> 6;
    const int j    = lane & 15;
    const int g    = lane >> 4;

    const int b    = blockIdx.x >> 6;
    const int sblk = (blockIdx.x & 63) * 64;

    // coalesced x tile load: 8 x (256 lanes x 16B contiguous)
    const float* xbase = x + ((size_t)b * S_ + sblk) * D_;
#pragma unroll
    for (int i = 0; i < 8; ++i) {
        const int idx = i * 1024 + tid * 4;      // 0..8191
        const int row = idx >> 7, col = idx & 127;
        *(f32x4*)&xlds[row * 132 + col] = *(const f32x4*)(xbase + idx);
    }
    __syncthreads();

    // A fragments from LDS (row = wv*16+j, chunk kk*32 + g*8; 2-way banks = free)
    s16x8 af[4];
#pragma unroll
    for (int kk = 0; kk < 4; ++kk)
        af[kk] = load_cvt8(&xlds[(wv * 16 + j) * 132 + kk * 32 + g * 8]);

    const int wrow = tid >> 1;
    const int wcol = (tid & 1) * 64;

#pragma unroll 1
    for (int m = 0; m < 3; ++m) {
        const float* Wm = (m == 0) ? Wq : (m == 1) ? Wk : Wv;
        __syncthreads();
#pragma unroll
        for (int it = 0; it < 8; ++it) {
            int col = wcol + it * 8;
            *(s16x8*)&wlds[wrow * 136 + col] = load_cvt8(Wm + wrow * 128 + col);
        }
        __syncthreads();

        f32x4 acc[8];
#pragma unroll
        for (int ct = 0; ct < 8; ++ct) { f32x4 z = {0.f, 0.f, 0.f, 0.f}; acc[ct] = z; }
#pragma unroll
        for (int ct = 0; ct < 8; ++ct) {
#pragma unroll
            for (int kk = 0; kk < 4; ++kk) {
                s16x8 bf = *(const s16x8*)&wlds[(ct * 16 + j) * 136 + kk * 32 + g * 8];
                acc[ct] = __builtin_amdgcn_mfma_f32_16x16x32_bf16(af[kk], bf, acc[ct], 0, 0, 0);
            }
        }

        if (m < 2) {
            const float* lw = (m == 0) ? qn_w : kn_w;
            const float* lb = (m == 0) ? qn_b : kn_b;
            float sum[4], sq[4];
#pragma unroll
            for (int r = 0; r < 4; ++r) {
                float s1 = 0.f, s2 = 0.f;
#pragma unroll
                for (int ct = 0; ct < 8; ++ct) { float v = acc[ct][r]; s1 += v; s2 += v * v; }
#pragma unroll
                for (int msk = 1; msk < 16; msk <<= 1) {
                    s1 += __shfl_xor(s1, msk);
                    s2 += __shfl_xor(s2, msk);
                }
                sum[r] = s1; sq[r] = s2;
            }
            float gwv[8], gbv[8];
#pragma unroll
            for (int ct = 0; ct < 8; ++ct) { gwv[ct] = lw[ct * 16 + j]; gbv[ct] = lb[ct * 16 + j]; }
            unsigned short* dst = (m == 0) ? qo : ko;
            // q: fold 1/sqrt(128) * log2(e) so scores are in exp2 domain
            const float post = (m == 0) ? 0.12751742361888f : 1.0f;
#pragma unroll
            for (int r = 0; r < 4; ++r) {
                float mean = sum[r] * (1.f / 128.f);
                float var  = sq[r] * (1.f / 128.f) - mean * mean;
                float rstd = rsqrtf(var + 1e-5f);
                size_t rowoff = ((size_t)b * S_ + sblk + wv * 16 + g * 4 + r) * D_;
#pragma unroll
                for (int ct = 0; ct < 8; ++ct) {
                    float val = ((acc[ct][r] - mean) * rstd * gwv[ct] + gbv[ct]) * post;
                    dst[rowoff + ct * 16 + j] = f2bf(val);
                }
            }
        } else {
#pragma unroll
            for (int ct = 0; ct < 8; ++ct) {
#pragma unroll
                for (int r = 0; r < 4; ++r) {
                    vstage[(ct * 16 + j) * 72 + wv * 16 + g * 4 + r] = f2bf(acc[ct][r]);
                }
            }
            __syncthreads();
            int h  = tid >> 1;
            int cb = (tid & 1) * 32;
#pragma unroll
            for (int c = 0; c < 4; ++c) {
                *(s16x8*)(vto + ((size_t)b * D_ + h) * S_ + sblk + cb + c * 8) =
                    *(const s16x8*)&vstage[h * 72 + cb + c * 8];
            }
        }
    }
}

// ---------------------------------------------------------------------------
// Kernel 2: flash attention — r13 skeleton (best measured: 99.4 us) with ONE
// change: V-fragment reads moved BEFORE QK^T (right after PV_PREV consumes
// the previous tile's vfr). Their LDS latency hides under QK's 16 MFMAs and
// the pre-barrier lgkmcnt(0) drain shortens accordingly.
// - 16x16 MFMAs, split-K x2 (2 qg x 2 kh waves, 32 q-rows/wave), T15
//   pipeline (PV(t-1) under K-read latency), 2-buffer gld16 staging,
//   vmcnt(8), 2 barriers/tile, grid 512 = 2 independent blocks/CU.
// - K [64][128]: slot = chunk ^ fK(row), fK = (row&3)|(((row>>3)&3)<<2);
//   fK(prow)==j for all read rows -> slot = chunk^j, full 16-slot spread.
// - V sub-tiled [buf][ksub][128][32] (64B rows), slot ^= (row^(row>>2))&3.
// - anti-lockstep stagger (odd blocks start at tile NT/2), zero-shuffle P,
//   ones-MFMA row-sum, exp2 domain (no max tracking; LayerNorm bounds
//   |s*log2e| <= 16.4), v_cvt_pk_bf16_f32, XCD swizzle.
// ---------------------------------------------------------------------------
__global__ __launch_bounds__(256, 2) void attn_kernel(
    const unsigned short* __restrict__ qb, const unsigned short* __restrict__ kb,
    const unsigned short* __restrict__ vtb, float* __restrict__ out)
{
    __shared__ unsigned short kbuf[2][KVB * D_];        // [64][128] 16 KiB each
    __shared__ unsigned short vbuf[2][2][D_ * 32];      // [ksub][128][32] 8 KiB each

    const int tid  = threadIdx.x;
    const int lane = tid & 63;
    const int wv   = tid >> 6;          // 0..3
    const int qg   = wv & 1;            // q-group (32 rows)
    const int kh   = wv >> 1;           // k-half (32 of 64)
    const int j    = lane & 15;
    const int g    = lane >> 4;

    // bijective XCD swizzle (512 % 8 == 0): XCD i gets batch i
    const int swz = (blockIdx.x & 7) * 64 + (blockIdx.x >> 3);
    const int b   = swz >> 6;
    const int s0  = (swz & 63) * 64;    // 64 q-rows per block

    // anti-lockstep: odd blocks within an XCD start half-way around the k-loop
    const int koff = ((blockIdx.x >> 3) & 1) * (NT / 2);

    // Q fragments: set qs=0 -> rows s0+qg*32+j, qs=1 -> +16
    const unsigned short* qr0 = qb + ((size_t)b * S_ + s0 + qg * 32 + j) * D_;
    const unsigned short* qr1 = qr0 + 16 * D_;
    s16x8 qf0[4], qf1[4];
#pragma unroll
    for (int kk = 0; kk < 4; ++kk) {
        qf0[kk] = *(const s16x8*)(qr0 + kk * 32 + g * 8);
        qf1[kk] = *(const s16x8*)(qr1 + kk * 32 + g * 8);
    }

    const unsigned short* kg_base = kb  + (size_t)b * S_ * D_;
    const unsigned short* vg_base = vtb + (size_t)b * D_ * S_;

    // stage PHYSICAL tile kt2 into buffer bi: 8 gld16/wave (4 K + 4 V)
    auto STAGE = [&](int bi, int kt2) {
        const int kv0 = kt2 * KVB;
#pragma unroll
        for (int it = 0; it < 4; ++it) {                 // K: 4 rows per issue
            const int row = wv * 16 + it * 4 + (lane >> 4);
            const int fk  = (row & 3) | (((row >> 3) & 3) << 2);
            const unsigned short* src =
                kg_base + (size_t)(kv0 + row) * D_ + (((lane & 15) ^ fk) << 3);
            gld16(&kbuf[bi][(wv * 16 + it * 4) * D_], src);
        }
        // V: wave handles ksub = wv&1, rows 64*(wv>>1) + it*16 .. +16
        const int ksub = wv & 1;
        const int rb   = 64 * (wv >> 1);
#pragma unroll
        for (int it = 0; it < 4; ++it) {
            const int row = rb + it * 16 + (lane >> 2);
            const int gg  = (row ^ (row >> 2)) & 3;
            const unsigned short* src =
                vg_base + (size_t)row * S_ + kv0 + ksub * 32 + (((lane & 3) ^ gg) << 3);
            gld16(&vbuf[bi][ksub][(rb + it * 16) * 32], src);
        }
    };

    STAGE(0, koff);
    STAGE(1, (1 + koff) & (NT - 1));

    f32x4 acc[2][8];
#pragma unroll
    for (int qs = 0; qs < 2; ++qs)
#pragma unroll
        for (int ht = 0; ht < 8; ++ht) { f32x4 z = {0.f,0.f,0.f,0.f}; acc[qs][ht] = z; }
    f32x4 acc_l[2];
    { f32x4 z = {0.f,0.f,0.f,0.f}; acc_l[0] = z; acc_l[1] = z; }

    // ones B-fragment (bf16 1.0 = 0x3F80) for the row-sum MFMA
    s16x8 ones;
#pragma unroll
    for (int e = 0; e < 8; ++e) ones[e] = (short)0x3F80;

    // loop-invariant addressing (zero-shuffle permutation).
    // fK(prow0) == fK(prow1) == j for both k-halves.
    const int prow0 = 8 * (j >> 2) + (j & 3) + 32 * kh;
    const int prow1 = prow0 + 4;

    // pipeline state carried across iterations
    s16x8 vfr[8];                        // V frags of tile t (PV at t+1)
    union PU { unsigned u[4]; s16x8 v; };
    PU P0, P1;                           // P frags of tile t (q-sets 0/1)

    // PV for the PREVIOUS tile: pure register MFMAs
    auto PV_PREV = [&]() {
        __builtin_amdgcn_s_setprio(1);
        acc_l[0] = __builtin_amdgcn_mfma_f32_16x16x32_bf16(P0.v, ones, acc_l[0], 0, 0, 0);
        acc_l[1] = __builtin_amdgcn_mfma_f32_16x16x32_bf16(P1.v, ones, acc_l[1], 0, 0, 0);
#pragma unroll
        for (int ht = 0; ht < 8; ++ht) {
            acc[0][ht] = __builtin_amdgcn_mfma_f32_16x16x32_bf16(P0.v, vfr[ht], acc[0][ht], 0, 0, 0);
            acc[1][ht] = __builtin_amdgcn_mfma_f32_16x16x32_bf16(P1.v, vfr[ht], acc[1][ht], 0, 0, 0);
        }
        __builtin_amdgcn_s_setprio(0);
    };

#pragma unroll 1
    for (int kt = 0; kt < NT; ++kt) {
        const int cur = kt & 1;
        if (kt + 1 < NT) { asm volatile("s_waitcnt vmcnt(8)" ::: "memory"); }
        else             { asm volatile("s_waitcnt vmcnt(0)" ::: "memory"); }
        __builtin_amdgcn_s_barrier();
        asm volatile("" ::: "memory");

        const unsigned short* kl = kbuf[cur];
        const unsigned short* vl = vbuf[cur][kh];

        // K fragment reads: chunk (4kk+g) of permuted rows prow0/prow1
        s16x8 kf[8];
#pragma unroll
        for (int kk = 0; kk < 4; ++kk) {
            const int cs = (((kk * 4 + g) ^ j) << 3);
            kf[kk * 2 + 0] = *(const s16x8*)&kl[prow0 * D_ + cs];
            kf[kk * 2 + 1] = *(const s16x8*)&kl[prow1 * D_ + cs];
        }

        // PV of previous tile (register-only; overlaps K-read latency,
        // consumes the OLD vfr before the overwrite below)
        if (kt) PV_PREV();

        // V fragment reads for THIS tile, issued BEFORE QK so their latency
        // hides under the 16 QK MFMAs (consumed at t+1)
#pragma unroll
        for (int ht = 0; ht < 8; ++ht) {
            const int row = ht * 16 + j;
            const int gg  = (row ^ (row >> 2)) & 3;
            vfr[ht] = *(const s16x8*)&vl[row * 32 + ((g ^ gg) << 3)];
        }

        // QK^T over this wave's 32-k half; both q-sets share each K fragment.
        f32x4 sv[2][2];
#pragma unroll
        for (int qs = 0; qs < 2; ++qs) {
            f32x4 z = {0.f,0.f,0.f,0.f}; sv[qs][0] = z; sv[qs][1] = z;
        }
        __builtin_amdgcn_s_setprio(1);
#pragma unroll
        for (int kk = 0; kk < 4; ++kk) {
            sv[0][0] = __builtin_amdgcn_mfma_f32_16x16x32_bf16(kf[kk*2+0], qf0[kk], sv[0][0], 0, 0, 0);
            sv[1][0] = __builtin_amdgcn_mfma_f32_16x16x32_bf16(kf[kk*2+0], qf1[kk], sv[1][0], 0, 0, 0);
            sv[0][1] = __builtin_amdgcn_mfma_f32_16x16x32_bf16(kf[kk*2+1], qf0[kk], sv[0][1], 0, 0, 0);
            sv[1][1] = __builtin_amdgcn_mfma_f32_16x16x32_bf16(kf[kk*2+1], qf1[kk], sv[1][1], 0, 0, 0);
        }
        __builtin_amdgcn_s_setprio(0);

        // no max tracking: P = exp2(s) directly (LayerNorm bounds |s| <= 16.4)
        float p0[8], p1[8];
#pragma unroll
        for (int r = 0; r < 4; ++r) {
            p0[r]     = exp2f(sv[0][0][r]);
            p0[4 + r] = exp2f(sv[0][1][r]);
            p1[r]     = exp2f(sv[1][0][r]);
            p1[4 + r] = exp2f(sv[1][1][r]);
        }
        P0.u[0] = cvt_pk(p0[0], p0[1]); P0.u[1] = cvt_pk(p0[2], p0[3]);
        P0.u[2] = cvt_pk(p0[4], p0[5]); P0.u[3] = cvt_pk(p0[6], p0[7]);
        P1.u[0] = cvt_pk(p1[0], p1[1]); P1.u[1] = cvt_pk(p1[2], p1[3]);
        P1.u[2] = cvt_pk(p1[4], p1[5]); P1.u[3] = cvt_pk(p1[6], p1[7]);

        // all LDS reads of buffer `cur` complete before anyone restages it
        asm volatile("s_waitcnt lgkmcnt(0)" ::: "memory");
        __builtin_amdgcn_s_barrier();
        asm volatile("" ::: "memory");
        if (kt + 2 < NT) STAGE(cur, (kt + 2 + koff) & (NT - 1));
    }

    // drain the pipeline: PV of the last tile
    PV_PREV();

    // all waves done with kbuf/vbuf before reusing them for the combine
    __syncthreads();

    // ---- split-k combine: kh=1 waves dump partials to LDS, kh=0 waves add,
    //      normalize, store.
    float* csum = (float*)&kbuf[0][0];   // 32 KiB: [qg][qs][ht][lane] f32x4
    float* lsum = (float*)&vbuf[0][0][0];// 4 KiB:  [qg][qs][lane] f32x4
    if (kh == 1) {
#pragma unroll
        for (int qs = 0; qs < 2; ++qs) {
#pragma unroll
            for (int ht = 0; ht < 8; ++ht)
                *(f32x4*)&csum[(((qg * 2 + qs) * 8 + ht) * 64 + lane) * 4] = acc[qs][ht];
            *(f32x4*)&lsum[((qg * 2 + qs) * 64 + lane) * 4] = acc_l[qs];
        }
    }
    __syncthreads();
    if (kh == 0) {
#pragma unroll
        for (int qs = 0; qs < 2; ++qs) {
            f32x4 lt = *(const f32x4*)&lsum[((qg * 2 + qs) * 64 + lane) * 4];
            f32x4 li;
#pragma unroll
            for (int r = 0; r < 4; ++r) li[r] = 1.0f / (acc_l[qs][r] + lt[r]);
#pragma unroll
            for (int ht = 0; ht < 8; ++ht) {
                f32x4 o = *(const f32x4*)&csum[(((qg * 2 + qs) * 8 + ht) * 64 + lane) * 4];
                size_t base = ((size_t)b * S_ + s0 + qg * 32 + qs * 16 + g * 4) * D_ + ht * 16 + j;
                out[base         ] = (acc[qs][ht][0] + o[0]) * li[0];
                out[base +     D_] = (acc[qs][ht][1] + o[1]) * li[1];
                out[base + 2 * D_] = (acc[qs][ht][2] + o[2]) * li[2];
                out[base + 3 * D_] = (acc[qs][ht][3] + o[3]) * li[3];
            }
        }
    }
}

extern "C" void kernel_launch(void* const* d_in, const int* in_sizes, int n_in,
                              void* d_out, int out_size, void* d_ws, size_t ws_size,
                              hipStream_t stream) {
    const float* x    = (const float*)d_in[0];
    const float* Wq   = (const float*)d_in[1];
    const float* Wk   = (const float*)d_in[2];
    const float* Wv   = (const float*)d_in[3];
    const float* qn_w = (const float*)d_in[4];
    const float* qn_b = (const float*)d_in[5];
    const float* kn_w = (const float*)d_in[6];
    const float* kn_b = (const float*)d_in[7];
    float* out = (float*)d_out;

    const size_t n = (size_t)B_ * S_ * D_;
    unsigned short* qws  = (unsigned short*)d_ws;
    unsigned short* kws  = qws + n;
    unsigned short* vtws = kws + n;

    proj_kernel<<<512, 256, 0, stream>>>(x, Wq, Wk, Wv, qn_w, qn_b, kn_w, kn_b,
                                         qws, kws, vtws);
    attn_kernel<<<512, 256, 0, stream>>>(qws, kws, vtws, out);
}

// Round 17
// 113.894 us; speedup vs baseline: 1.2188x; 1.0271x over previous
//
#include <hip/hip_runtime.h>

#define B_ 8
#define S_ 4096
#define D_ 128
#define KVB 64
#define NT (S_ / KVB)

typedef __attribute__((ext_vector_type(4))) float f32x4;
typedef __attribute__((ext_vector_type(8))) short s16x8;

__device__ __forceinline__ unsigned short f2bf(float f) {
    union { float f; unsigned u; } v; v.f = f;
    unsigned r = (v.u + 0x7fffu + ((v.u >> 16) & 1u)) >> 16;
    return (unsigned short)r;
}

// packed f32x2 -> bf16x2 (RNE), single VALU op
__device__ __forceinline__ unsigned cvt_pk(float lo, float hi) {
    unsigned r;
    asm("v_cvt_pk_bf16_f32 %0, %1, %2" : "=v"(r) : "v"(lo), "v"(hi));
    return r;
}

__device__ __forceinline__ s16x8 load_cvt8(const float* p) {
    f32x4 a = *(const f32x4*)p;
    f32x4 b = *(const f32x4*)(p + 4);
    s16x8 r;
    r[0] = (short)f2bf(a[0]); r[1] = (short)f2bf(a[1]);
    r[2] = (short)f2bf(a[2]); r[3] = (short)f2bf(a[3]);
    r[4] = (short)f2bf(b[0]); r[5] = (short)f2bf(b[1]);
    r[6] = (short)f2bf(b[2]); r[7] = (short)f2bf(b[3]);
    return r;
}

// async global->LDS, 16B per lane. lds must be wave-uniform base; HW adds lane*16.
__device__ __forceinline__ void gld16(unsigned short* lds, const unsigned short* g) {
    __builtin_amdgcn_global_load_lds(
        (const __attribute__((address_space(1))) unsigned int*)g,
        (__attribute__((address_space(3))) unsigned int*)lds,
        16, 0, 0);
}

// ---------------------------------------------------------------------------
// Kernel 1: q/k/v projections + layernorm(q,k), bf16 outputs, v transposed.
// q is pre-scaled by (1/sqrt(D)) * log2(e) so attention works in exp2 domain.
// (r13 version — direct x loads; r16's LDS staging of x regressed ~4.5 us:
// x rows are single-use per block, so there was no over-fetch to fix.)
// ---------------------------------------------------------------------------
__global__ __launch_bounds__(256, 1) void proj_kernel(
    const float* __restrict__ x,  const float* __restrict__ Wq,
    const float* __restrict__ Wk, const float* __restrict__ Wv,
    const float* __restrict__ qn_w, const float* __restrict__ qn_b,
    const float* __restrict__ kn_w, const float* __restrict__ kn_b,
    unsigned short* __restrict__ qo, unsigned short* __restrict__ ko,
    unsigned short* __restrict__ vto)
{
    __shared__ unsigned short wlds[128 * 136];
    __shared__ unsigned short vstage[128 * 72];

    const int tid  = threadIdx.x;
    const int lane = tid & 63;
    const int wv   = tid >> 6;
    const int j    = lane & 15;
    const int g    = lane >> 4;

    const int b    = blockIdx.x >> 6;
    const int sblk = (blockIdx.x & 63) * 64;
    const int srow = sblk + wv * 16;

    const float* xrow = x + ((size_t)b * S_ + srow + j) * D_;
    s16x8 af[4];
#pragma unroll
    for (int kk = 0; kk < 4; ++kk) af[kk] = load_cvt8(xrow + kk * 32 + g * 8);

    const int wrow = tid >> 1;
    const int wcol = (tid & 1) * 64;

#pragma unroll 1
    for (int m = 0; m < 3; ++m) {
        const float* Wm = (m == 0) ? Wq : (m == 1) ? Wk : Wv;
        __syncthreads();
#pragma unroll
        for (int it = 0; it < 8; ++it) {
            int col = wcol + it * 8;
            *(s16x8*)&wlds[wrow * 136 + col] = load_cvt8(Wm + wrow * 128 + col);
        }
        __syncthreads();

        f32x4 acc[8];
#pragma unroll
        for (int ct = 0; ct < 8; ++ct) { f32x4 z = {0.f, 0.f, 0.f, 0.f}; acc[ct] = z; }
#pragma unroll
        for (int ct = 0; ct < 8; ++ct) {
#pragma unroll
            for (int kk = 0; kk < 4; ++kk) {
                s16x8 bf = *(const s16x8*)&wlds[(ct * 16 + j) * 136 + kk * 32 + g * 8];
                acc[ct] = __builtin_amdgcn_mfma_f32_16x16x32_bf16(af[kk], bf, acc[ct], 0, 0, 0);
            }
        }

        if (m < 2) {
            const float* lw = (m == 0) ? qn_w : kn_w;
            const float* lb = (m == 0) ? qn_b : kn_b;
            float sum[4], sq[4];
#pragma unroll
            for (int r = 0; r < 4; ++r) {
                float s1 = 0.f, s2 = 0.f;
#pragma unroll
                for (int ct = 0; ct < 8; ++ct) { float v = acc[ct][r]; s1 += v; s2 += v * v; }
#pragma unroll
                for (int msk = 1; msk < 16; msk <<= 1) {
                    s1 += __shfl_xor(s1, msk);
                    s2 += __shfl_xor(s2, msk);
                }
                sum[r] = s1; sq[r] = s2;
            }
            float gwv[8], gbv[8];
#pragma unroll
            for (int ct = 0; ct < 8; ++ct) { gwv[ct] = lw[ct * 16 + j]; gbv[ct] = lb[ct * 16 + j]; }
            unsigned short* dst = (m == 0) ? qo : ko;
            // q: fold 1/sqrt(128) * log2(e) so scores are in exp2 domain
            const float post = (m == 0) ? 0.12751742361888f : 1.0f;
#pragma unroll
            for (int r = 0; r < 4; ++r) {
                float mean = sum[r] * (1.f / 128.f);
                float var  = sq[r] * (1.f / 128.f) - mean * mean;
                float rstd = rsqrtf(var + 1e-5f);
                size_t rowoff = ((size_t)b * S_ + sblk + wv * 16 + g * 4 + r) * D_;
#pragma unroll
                for (int ct = 0; ct < 8; ++ct) {
                    float val = ((acc[ct][r] - mean) * rstd * gwv[ct] + gbv[ct]) * post;
                    dst[rowoff + ct * 16 + j] = f2bf(val);
                }
            }
        } else {
#pragma unroll
            for (int ct = 0; ct < 8; ++ct) {
#pragma unroll
                for (int r = 0; r < 4; ++r) {
                    vstage[(ct * 16 + j) * 72 + wv * 16 + g * 4 + r] = f2bf(acc[ct][r]);
                }
            }
            __syncthreads();
            int h  = tid >> 1;
            int cb = (tid & 1) * 32;
#pragma unroll
            for (int c = 0; c < 4; ++c) {
                *(s16x8*)(vto + ((size_t)b * D_ + h) * S_ + sblk + cb + c * 8) =
                    *(const s16x8*)&vstage[h * 72 + cb + c * 8];
            }
        }
    }
}

// ---------------------------------------------------------------------------
// Kernel 2: flash attention — r16 version unchanged (best measured: 94.5 us).
// - 16x16 MFMAs, split-K x2 (2 qg x 2 kh waves, 32 q-rows/wave), T15
//   pipeline: PV(t-1) under K-read latency, V(t) reads issued BEFORE QK so
//   their latency hides under the 16 QK MFMAs. 2-buffer gld16 staging,
//   vmcnt(8), 2 barriers/tile, grid 512 = 2 independent blocks/CU.
// - K [64][128]: slot = chunk ^ fK(row), fK = (row&3)|(((row>>3)&3)<<2);
//   fK(prow)==j for all read rows -> slot = chunk^j, full 16-slot spread.
// - V sub-tiled [buf][ksub][128][32] (64B rows), slot ^= (row^(row>>2))&3.
// - anti-lockstep stagger (odd blocks start at tile NT/2), zero-shuffle P,
//   ones-MFMA row-sum, exp2 domain (no max tracking; LayerNorm bounds
//   |s*log2e| <= 16.4), v_cvt_pk_bf16_f32, XCD swizzle.
// ---------------------------------------------------------------------------
__global__ __launch_bounds__(256, 2) void attn_kernel(
    const unsigned short* __restrict__ qb, const unsigned short* __restrict__ kb,
    const unsigned short* __restrict__ vtb, float* __restrict__ out)
{
    __shared__ unsigned short kbuf[2][KVB * D_];        // [64][128] 16 KiB each
    __shared__ unsigned short vbuf[2][2][D_ * 32];      // [ksub][128][32] 8 KiB each

    const int tid  = threadIdx.x;
    const int lane = tid & 63;
    const int wv   = tid >> 6;          // 0..3
    const int qg   = wv & 1;            // q-group (32 rows)
    const int kh   = wv >> 1;           // k-half (32 of 64)
    const int j    = lane & 15;
    const int g    = lane >> 4;

    // bijective XCD swizzle (512 % 8 == 0): XCD i gets batch i
    const int swz = (blockIdx.x & 7) * 64 + (blockIdx.x >> 3);
    const int b   = swz >> 6;
    const int s0  = (swz & 63) * 64;    // 64 q-rows per block

    // anti-lockstep: odd blocks within an XCD start half-way around the k-loop
    const int koff = ((blockIdx.x >> 3) & 1) * (NT / 2);

    // Q fragments: set qs=0 -> rows s0+qg*32+j, qs=1 -> +16
    const unsigned short* qr0 = qb + ((size_t)b * S_ + s0 + qg * 32 + j) * D_;
    const unsigned short* qr1 = qr0 + 16 * D_;
    s16x8 qf0[4], qf1[4];
#pragma unroll
    for (int kk = 0; kk < 4; ++kk) {
        qf0[kk] = *(const s16x8*)(qr0 + kk * 32 + g * 8);
        qf1[kk] = *(const s16x8*)(qr1 + kk * 32 + g * 8);
    }

    const unsigned short* kg_base = kb  + (size_t)b * S_ * D_;
    const unsigned short* vg_base = vtb + (size_t)b * D_ * S_;

    // stage PHYSICAL tile kt2 into buffer bi: 8 gld16/wave (4 K + 4 V)
    auto STAGE = [&](int bi, int kt2) {
        const int kv0 = kt2 * KVB;
#pragma unroll
        for (int it = 0; it < 4; ++it) {                 // K: 4 rows per issue
            const int row = wv * 16 + it * 4 + (lane >> 4);
            const int fk  = (row & 3) | (((row >> 3) & 3) << 2);
            const unsigned short* src =
                kg_base + (size_t)(kv0 + row) * D_ + (((lane & 15) ^ fk) << 3);
            gld16(&kbuf[bi][(wv * 16 + it * 4) * D_], src);
        }
        // V: wave handles ksub = wv&1, rows 64*(wv>>1) + it*16 .. +16
        const int ksub = wv & 1;
        const int rb   = 64 * (wv >> 1);
#pragma unroll
        for (int it = 0; it < 4; ++it) {
            const int row = rb + it * 16 + (lane >> 2);
            const int gg  = (row ^ (row >> 2)) & 3;
            const unsigned short* src =
                vg_base + (size_t)row * S_ + kv0 + ksub * 32 + (((lane & 3) ^ gg) << 3);
            gld16(&vbuf[bi][ksub][(rb + it * 16) * 32], src);
        }
    };

    STAGE(0, koff);
    STAGE(1, (1 + koff) & (NT - 1));

    f32x4 acc[2][8];
#pragma unroll
    for (int qs = 0; qs < 2; ++qs)
#pragma unroll
        for (int ht = 0; ht < 8; ++ht) { f32x4 z = {0.f,0.f,0.f,0.f}; acc[qs][ht] = z; }
    f32x4 acc_l[2];
    { f32x4 z = {0.f,0.f,0.f,0.f}; acc_l[0] = z; acc_l[1] = z; }

    // ones B-fragment (bf16 1.0 = 0x3F80) for the row-sum MFMA
    s16x8 ones;
#pragma unroll
    for (int e = 0; e < 8; ++e) ones[e] = (short)0x3F80;

    // loop-invariant addressing (zero-shuffle permutation).
    // fK(prow0) == fK(prow1) == j for both k-halves.
    const int prow0 = 8 * (j >> 2) + (j & 3) + 32 * kh;
    const int prow1 = prow0 + 4;

    // pipeline state carried across iterations
    s16x8 vfr[8];                        // V frags of tile t (PV at t+1)
    union PU { unsigned u[4]; s16x8 v; };
    PU P0, P1;                           // P frags of tile t (q-sets 0/1)

    // PV for the PREVIOUS tile: pure register MFMAs
    auto PV_PREV = [&]() {
        __builtin_amdgcn_s_setprio(1);
        acc_l[0] = __builtin_amdgcn_mfma_f32_16x16x32_bf16(P0.v, ones, acc_l[0], 0, 0, 0);
        acc_l[1] = __builtin_amdgcn_mfma_f32_16x16x32_bf16(P1.v, ones, acc_l[1], 0, 0, 0);
#pragma unroll
        for (int ht = 0; ht < 8; ++ht) {
            acc[0][ht] = __builtin_amdgcn_mfma_f32_16x16x32_bf16(P0.v, vfr[ht], acc[0][ht], 0, 0, 0);
            acc[1][ht] = __builtin_amdgcn_mfma_f32_16x16x32_bf16(P1.v, vfr[ht], acc[1][ht], 0, 0, 0);
        }
        __builtin_amdgcn_s_setprio(0);
    };

#pragma unroll 1
    for (int kt = 0; kt < NT; ++kt) {
        const int cur = kt & 1;
        if (kt + 1 < NT) { asm volatile("s_waitcnt vmcnt(8)" ::: "memory"); }
        else             { asm volatile("s_waitcnt vmcnt(0)" ::: "memory"); }
        __builtin_amdgcn_s_barrier();
        asm volatile("" ::: "memory");

        const unsigned short* kl = kbuf[cur];
        const unsigned short* vl = vbuf[cur][kh];

        // K fragment reads: chunk (4kk+g) of permuted rows prow0/prow1
        s16x8 kf[8];
#pragma unroll
        for (int kk = 0; kk < 4; ++kk) {
            const int cs = (((kk * 4 + g) ^ j) << 3);
            kf[kk * 2 + 0] = *(const s16x8*)&kl[prow0 * D_ + cs];
            kf[kk * 2 + 1] = *(const s16x8*)&kl[prow1 * D_ + cs];
        }

        // PV of previous tile (register-only; overlaps K-read latency,
        // consumes the OLD vfr before the overwrite below)
        if (kt) PV_PREV();

        // V fragment reads for THIS tile, issued BEFORE QK so their latency
        // hides under the 16 QK MFMAs (consumed at t+1)
#pragma unroll
        for (int ht = 0; ht < 8; ++ht) {
            const int row = ht * 16 + j;
            const int gg  = (row ^ (row >> 2)) & 3;
            vfr[ht] = *(const s16x8*)&vl[row * 32 + ((g ^ gg) << 3)];
        }

        // QK^T over this wave's 32-k half; both q-sets share each K fragment.
        f32x4 sv[2][2];
#pragma unroll
        for (int qs = 0; qs < 2; ++qs) {
            f32x4 z = {0.f,0.f,0.f,0.f}; sv[qs][0] = z; sv[qs][1] = z;
        }
        __builtin_amdgcn_s_setprio(1);
#pragma unroll
        for (int kk = 0; kk < 4; ++kk) {
            sv[0][0] = __builtin_amdgcn_mfma_f32_16x16x32_bf16(kf[kk*2+0], qf0[kk], sv[0][0], 0, 0, 0);
            sv[1][0] = __builtin_amdgcn_mfma_f32_16x16x32_bf16(kf[kk*2+0], qf1[kk], sv[1][0], 0, 0, 0);
            sv[0][1] = __builtin_amdgcn_mfma_f32_16x16x32_bf16(kf[kk*2+1], qf0[kk], sv[0][1], 0, 0, 0);
            sv[1][1] = __builtin_amdgcn_mfma_f32_16x16x32_bf16(kf[kk*2+1], qf1[kk], sv[1][1], 0, 0, 0);
        }
        __builtin_amdgcn_s_setprio(0);

        // no max tracking: P = exp2(s) directly (LayerNorm bounds |s| <= 16.4)
        float p0[8], p1[8];
#pragma unroll
        for (int r = 0; r < 4; ++r) {
            p0[r]     = exp2f(sv[0][0][r]);
            p0[4 + r] = exp2f(sv[0][1][r]);
            p1[r]     = exp2f(sv[1][0][r]);
            p1[4 + r] = exp2f(sv[1][1][r]);
        }
        P0.u[0] = cvt_pk(p0[0], p0[1]); P0.u[1] = cvt_pk(p0[2], p0[3]);
        P0.u[2] = cvt_pk(p0[4], p0[5]); P0.u[3] = cvt_pk(p0[6], p0[7]);
        P1.u[0] = cvt_pk(p1[0], p1[1]); P1.u[1] = cvt_pk(p1[2], p1[3]);
        P1.u[2] = cvt_pk(p1[4], p1[5]); P1.u[3] = cvt_pk(p1[6], p1[7]);

        // all LDS reads of buffer `cur` complete before anyone restages it
        asm volatile("s_waitcnt lgkmcnt(0)" ::: "memory");
        __builtin_amdgcn_s_barrier();
        asm volatile("" ::: "memory");
        if (kt + 2 < NT) STAGE(cur, (kt + 2 + koff) & (NT - 1));
    }

    // drain the pipeline: PV of the last tile
    PV_PREV();

    // all waves done with kbuf/vbuf before reusing them for the combine
    __syncthreads();

    // ---- split-k combine: kh=1 waves dump partials to LDS, kh=0 waves add,
    //      normalize, store.
    float* csum = (float*)&kbuf[0][0];   // 32 KiB: [qg][qs][ht][lane] f32x4
    float* lsum = (float*)&vbuf[0][0][0];// 4 KiB:  [qg][qs][lane] f32x4
    if (kh == 1) {
#pragma unroll
        for (int qs = 0; qs < 2; ++qs) {
#pragma unroll
            for (int ht = 0; ht < 8; ++ht)
                *(f32x4*)&csum[(((qg * 2 + qs) * 8 + ht) * 64 + lane) * 4] = acc[qs][ht];
            *(f32x4*)&lsum[((qg * 2 + qs) * 64 + lane) * 4] = acc_l[qs];
        }
    }
    __syncthreads();
    if (kh == 0) {
#pragma unroll
        for (int qs = 0; qs < 2; ++qs) {
            f32x4 lt = *(const f32x4*)&lsum[((qg * 2 + qs) * 64 + lane) * 4];
            f32x4 li;
#pragma unroll
            for (int r = 0; r < 4; ++r) li[r] = 1.0f / (acc_l[qs][r] + lt[r]);
#pragma unroll
            for (int ht = 0; ht < 8; ++ht) {
                f32x4 o = *(const f32x4*)&csum[(((qg * 2 + qs) * 8 + ht) * 64 + lane) * 4];
                size_t base = ((size_t)b * S_ + s0 + qg * 32 + qs * 16 + g * 4) * D_ + ht * 16 + j;
                out[base         ] = (acc[qs][ht][0] + o[0]) * li[0];
                out[base +     D_] = (acc[qs][ht][1] + o[1]) * li[1];
                out[base + 2 * D_] = (acc[qs][ht][2] + o[2]) * li[2];
                out[base + 3 * D_] = (acc[qs][ht][3] + o[3]) * li[3];
            }
        }
    }
}

extern "C" void kernel_launch(void* const* d_in, const int* in_sizes, int n_in,
                              void* d_out, int out_size, void* d_ws, size_t ws_size,
                              hipStream_t stream) {
    const float* x    = (const float*)d_in[0];
    const float* Wq   = (const float*)d_in[1];
    const float* Wk   = (const float*)d_in[2];
    const float* Wv   = (const float*)d_in[3];
    const float* qn_w = (const float*)d_in[4];
    const float* qn_b = (const float*)d_in[5];
    const float* kn_w = (const float*)d_in[6];
    const float* kn_b = (const float*)d_in[7];
    float* out = (float*)d_out;

    const size_t n = (size_t)B_ * S_ * D_;
    unsigned short* qws  = (unsigned short*)d_ws;
    unsigned short* kws  = qws + n;
    unsigned short* vtws = kws + n;

    proj_kernel<<<512, 256, 0, stream>>>(x, Wq, Wk, Wv, qn_w, qn_b, kn_w, kn_b,
                                         qws, kws, vtws);
    attn_kernel<<<512, 256, 0, stream>>>(qws, kws, vtws, out);
}